// Round 5
// baseline (212.818 us; speedup 1.0000x reference)
//
#include <hip/hip_runtime.h>
#include <math.h>

// Problem constants (fixed by setup_inputs)
constexpr int B_  = 8;
constexpr int T_  = 12;
constexpr int N_  = 512;
constexpr int DM  = 128;      // d_model
constexpr int KH  = 8;        // heads
constexpr int DH  = 16;       // head dim
constexpr int MR  = B_*T_*N_; // 49152 rows
constexpr int K3  = 3*DM;     // 384
constexpr int TB  = 256;

typedef __attribute__((ext_vector_type(8))) short  bf16x8;
typedef __attribute__((ext_vector_type(4))) float  f32x4;
typedef __attribute__((ext_vector_type(4))) int    i32x4;

// log2(e) and the constant softmax shift (in log2 domain)
#define LOG2E 1.44269504088896340736f
#define SHIFT2 28.8539008177792681f     /* 20 * log2(e) */

// fp32 -> bf16 RNE (inputs here are finite, non-NaN)
static __device__ inline unsigned short f2bf(float x) {
    unsigned u = __float_as_uint(x);
    return (unsigned short)((u + 0x7fffu + ((u >> 16) & 1u)) >> 16);
}
// pack two fp32 -> bf16x2 dword, round half up (a -> low16, b -> high16)
static __device__ inline unsigned pk2(float a, float b) {
    unsigned ua = __float_as_uint(a) + 0x8000u;
    unsigned ub = __float_as_uint(b) + 0x8000u;
    return __builtin_amdgcn_perm(ub, ua, 0x07060302u);
}
// pack two fp32 -> bf16x2 dword, TRUNCATE (1 v_perm). Used for P: the
// truncation bias cancels since l sums the same truncated values.
static __device__ inline unsigned pk2t(float a, float b) {
    return __builtin_amdgcn_perm(__float_as_uint(b), __float_as_uint(a),
                                 0x07060302u);
}
static __device__ inline float fast_rcp(float x) {
#if __has_builtin(__builtin_amdgcn_rcpf)
    return __builtin_amdgcn_rcpf(x);
#else
    return 1.0f / x;
#endif
}

// ---------------------------------------------------------------------------
// Kernel 0: weight prep. Wt[p][n][k] = bf16(W_p[k][n]); Wot[n][k] = bf16(Wo[k][n]).
// ---------------------------------------------------------------------------
__global__ __launch_bounds__(256) void wprep_kernel(
    const float* __restrict__ Wq, const float* __restrict__ Wk,
    const float* __restrict__ Wv, const float* __restrict__ Wo,
    unsigned short* __restrict__ Wt, unsigned short* __restrict__ Wot)
{
    const int idx = blockIdx.x*256 + threadIdx.x;
    if (idx < 3*K3*DM) {
        const int p   = idx / (K3*DM);
        const int rem = idx - p*(K3*DM);     // k*128 + n
        const int k   = rem >> 7;
        const int n   = rem & 127;
        const float* W = (p == 0) ? Wq : ((p == 1) ? Wk : Wv);
        Wt[p*(K3*DM) + n*K3 + k] = f2bf(W[rem]);
    } else {
        const int i2 = idx - 3*K3*DM;        // k*128 + n
        const int k  = i2 >> 7;
        const int n  = i2 & 127;
        Wot[n*DM + k] = f2bf(Wo[i2]);
    }
}

// ---------------------------------------------------------------------------
// Kernel 1: q/k/v = relu([X|STE] @ W{q,k,v} + b) via bf16 MFMA.
// Tile 128x128x(K=64 chunks); 4 waves 2x2. H fp32->bf16 during staging.
// Output head-major bf16 [KH][MR][DH]; q pre-scaled by 0.25*log2(e) so the
// attention scores come out of the S-MFMA already in log2 domain.
// ---------------------------------------------------------------------------
__global__ __launch_bounds__(256, 2) void qkv_mfma(
    const float* __restrict__ X, const float* __restrict__ STE,
    const unsigned short* __restrict__ Wt,
    const float* __restrict__ bq, const float* __restrict__ bk,
    const float* __restrict__ bv,
    unsigned short* __restrict__ qb, unsigned short* __restrict__ kb2,
    unsigned short* __restrict__ vb2)
{
    __shared__ __align__(16) unsigned short Ash[128*72];  // [m][k] 18 KB
    __shared__ __align__(16) unsigned short Bsh[128*72];  // [n][k] 18 KB
    const int tid = threadIdx.x;
    const int rb  = blockIdx.x * 128;
    const int p   = blockIdx.y;            // 0:q 1:k 2:v (uniform)
    const unsigned short* __restrict__ wtp = Wt + p*(K3*DM);
    const float* __restrict__ bias = (p == 0) ? bq : ((p == 1) ? bk : bv);
    unsigned short* __restrict__ outb = (p == 0) ? qb : ((p == 1) ? kb2 : vb2);
    const float scale = (p == 0) ? (0.25f * LOG2E) : 1.0f;

    const int lane = tid & 63, wv = tid >> 6;
    const int wm = (wv >> 1)*64, wn = (wv & 1)*64;
    const int m15 = lane & 15, g = lane >> 4;

    f32x4 acc[4][4] = {};

    for (int kt = 0; kt < K3; kt += 64) {
        const float* __restrict__ src = (kt < DM) ? (X + kt) : (STE + (kt - DM));
        const int ldr = (kt < DM) ? DM : 2*DM;
        #pragma unroll
        for (int i = 0; i < 8; ++i) {
            const int idx = tid + i*TB;
            const int m   = idx >> 4;
            const int c4  = idx & 15;
            const float4 f = *(const float4*)(src + (rb + m)*ldr + c4*4);
            uint2 d2;
            d2.x = pk2(f.x, f.y);
            d2.y = pk2(f.z, f.w);
            *(uint2*)(Ash + m*72 + c4*4) = d2;
        }
        #pragma unroll
        for (int i = 0; i < 4; ++i) {
            const int idx = tid + i*TB;
            const int n   = idx >> 3;
            const int kg  = idx & 7;
            *(uint4*)(Bsh + n*72 + kg*8) =
                *(const uint4*)(wtp + n*K3 + kt + kg*8);
        }
        __syncthreads();
        #pragma unroll
        for (int ks = 0; ks < 64; ks += 32) {
            bf16x8 af[4], bf[4];
            #pragma unroll
            for (int i = 0; i < 4; ++i)
                af[i] = *(const bf16x8*)(Ash + (wm + i*16 + m15)*72 + ks + g*8);
            #pragma unroll
            for (int j = 0; j < 4; ++j)
                bf[j] = *(const bf16x8*)(Bsh + (wn + j*16 + m15)*72 + ks + g*8);
            #pragma unroll
            for (int i = 0; i < 4; ++i)
                #pragma unroll
                for (int j = 0; j < 4; ++j)
                    acc[i][j] = __builtin_amdgcn_mfma_f32_16x16x32_bf16(
                        af[i], bf[j], acc[i][j], 0, 0, 0);
        }
        __syncthreads();
    }

    #pragma unroll
    for (int j = 0; j < 4; ++j) {
        const int c  = wn + j*16 + m15;
        const float bj = bias[c];
        const int h = c >> 4, d = c & 15;
        #pragma unroll
        for (int i = 0; i < 4; ++i) {
            #pragma unroll
            for (int r = 0; r < 4; ++r) {
                const int row = rb + wm + i*16 + g*4 + r;
                float v = acc[i][j][r] + bj;
                v = (v > 0.f ? v : 0.f) * scale;
                outb[(h*MR + row)*DH + d] = f2bf(v);
            }
        }
    }
}

// ---------------------------------------------------------------------------
// Kernel 2: MFMA attention. Changes this round (all VALU -> MFMA shifts):
//  - S-MFMA accumulator seeded with -SHIFT2: p = exp2f(s), no per-elem sub.
//  - l computed by a ones-MFMA: lacc rows == O-acc rows on the same lane,
//    so normalization needs no shuffles at all.
//  - P packed to bf16 by truncation (1 v_perm/pair); bias cancels in l.
// ---------------------------------------------------------------------------
__global__ __launch_bounds__(256, 3) void attn_kernel(
    const unsigned short* __restrict__ qb, const unsigned short* __restrict__ kb,
    const unsigned short* __restrict__ vb, unsigned short* __restrict__ ob)
{
    __shared__ __align__(16) unsigned short Klds[N_*DH];    // 16 KB
    __shared__ __align__(16) unsigned short Vtlds[DH*536];  // [d][key]

    const int tid = threadIdx.x;
    const int h   = blockIdx.x & (KH-1);
    const int bt  = blockIdx.x >> 3;
    const int base = (h*MR + bt*N_) * DH;

    {
        const uint4* kg = (const uint4*)(kb + base);
        uint4* kl = (uint4*)Klds;
        #pragma unroll
        for (int i = 0; i < 4; ++i) kl[tid + i*TB] = kg[tid + i*TB];
    }
    {
        const unsigned* vg = (const unsigned*)(vb + base);
        unsigned a[8], b[8];
        #pragma unroll
        for (int j = 0; j < 8; ++j) {
            a[j] = vg[(2*tid)*8 + j];
            b[j] = vg[(2*tid+1)*8 + j];
        }
        unsigned* vt = (unsigned*)Vtlds;
        #pragma unroll
        for (int d = 0; d < 16; ++d) {
            const int sh = (d & 1) * 16;
            const unsigned lo = (a[d >> 1] >> sh) & 0xffffu;
            const unsigned hi = (b[d >> 1] >> sh) & 0xffffu;
            vt[d*268 + tid] = lo | (hi << 16);
        }
    }
    __syncthreads();

    const int wv   = tid >> 6;
    const int lane = tid & 63;
    const int m    = lane & 15;
    const int g    = lane >> 4;

    bf16x8 qf[8];
    const unsigned short* qp = qb + base;
    #pragma unroll
    for (int j = 0; j < 8; ++j) {
        bf16x8 t = {0,0,0,0,0,0,0,0};
        if (g < 2) t = *(const bf16x8*)(qp + ((wv*8 + j)*16 + m)*DH + g*8);
        qf[j] = t;
    }

    const bf16x8 ones = {0x3F80,0x3F80,0x3F80,0x3F80,0x3F80,0x3F80,0x3F80,0x3F80};
    const f32x4 zshift = {-SHIFT2, -SHIFT2, -SHIFT2, -SHIFT2};

    f32x4 acc[8]  = {};
    f32x4 lacc[8] = {};

    for (int c = 0; c < 16; ++c) {
        const int kr0 = c*32 + ((m & 12) << 1) + (m & 3);
        bf16x8 kf0 = {0,0,0,0,0,0,0,0};
        bf16x8 kf1 = {0,0,0,0,0,0,0,0};
        if (g < 2) {
            kf0 = *(const bf16x8*)(Klds + kr0*DH + g*8);
            kf1 = *(const bf16x8*)(Klds + (kr0 + 4)*DH + g*8);
        }
        const bf16x8 vf = *(const bf16x8*)(Vtlds + m*536 + c*32 + g*8);

        #pragma unroll
        for (int j = 0; j < 8; ++j) {
            f32x4 s0 = __builtin_amdgcn_mfma_f32_16x16x32_bf16(kf0, qf[j], zshift, 0, 0, 0);
            f32x4 s1 = __builtin_amdgcn_mfma_f32_16x16x32_bf16(kf1, qf[j], zshift, 0, 0, 0);
            // lane holds S2[q=m][key = c*32 + 8g + r (+4 for s1)] - SHIFT2
            const float p0 = exp2f(s0[0]);
            const float p1 = exp2f(s0[1]);
            const float p2 = exp2f(s0[2]);
            const float p3 = exp2f(s0[3]);
            const float p4 = exp2f(s1[0]);
            const float p5 = exp2f(s1[1]);
            const float p6 = exp2f(s1[2]);
            const float p7 = exp2f(s1[3]);
            i32x4 pd = { (int)pk2t(p0, p1), (int)pk2t(p2, p3),
                         (int)pk2t(p4, p5), (int)pk2t(p6, p7) };
            const bf16x8 pf = __builtin_bit_cast(bf16x8, pd);
            acc[j]  = __builtin_amdgcn_mfma_f32_16x16x32_bf16(pf, vf,   acc[j],  0, 0, 0);
            lacc[j] = __builtin_amdgcn_mfma_f32_16x16x32_bf16(pf, ones, lacc[j], 0, 0, 0);
        }
    }

    // epilogue: rows of lacc coincide with rows of acc on this lane.
    #pragma unroll
    for (int j = 0; j < 8; ++j) {
        #pragma unroll
        for (int r = 0; r < 4; ++r) {
            const float iv = fast_rcp(lacc[j][r]);
            const int qrow = bt*N_ + (wv*8 + j)*16 + 4*g + r;
            ob[qrow*DM + h*DH + m] = f2bf(acc[j][r] * iv);
        }
    }
}

// ---------------------------------------------------------------------------
// Kernel 3: out = relu(o @ Wo + bo) via bf16 MFMA. K=128 one staging phase.
// ---------------------------------------------------------------------------
__global__ __launch_bounds__(256, 2) void out_mfma(
    const unsigned short* __restrict__ ot, const unsigned short* __restrict__ Wot,
    const float* __restrict__ bo, float* __restrict__ out)
{
    __shared__ __align__(16) unsigned short Ash[128*136];  // 34 KB
    __shared__ __align__(16) unsigned short Bsh[128*136];  // 34 KB
    const int tid = threadIdx.x;
    const int rb  = blockIdx.x * 128;
    const int lane = tid & 63, wv = tid >> 6;
    const int wm = (wv >> 1)*64, wn = (wv & 1)*64;
    const int m15 = lane & 15, g = lane >> 4;

    #pragma unroll
    for (int i = 0; i < 8; ++i) {
        const int idx = tid + i*TB;          // 0..2047
        const int r  = idx >> 4;             // 0..127
        const int kg = idx & 15;             // 0..15
        *(uint4*)(Ash + r*136 + kg*8) = *(const uint4*)(ot + (rb + r)*DM + kg*8);
        *(uint4*)(Bsh + r*136 + kg*8) = *(const uint4*)(Wot + r*DM + kg*8);
    }
    __syncthreads();

    f32x4 acc[4][4] = {};
    #pragma unroll
    for (int ks = 0; ks < 128; ks += 32) {
        bf16x8 af[4], bf[4];
        #pragma unroll
        for (int i = 0; i < 4; ++i)
            af[i] = *(const bf16x8*)(Ash + (wm + i*16 + m15)*136 + ks + g*8);
        #pragma unroll
        for (int j = 0; j < 4; ++j)
            bf[j] = *(const bf16x8*)(Bsh + (wn + j*16 + m15)*136 + ks + g*8);
        #pragma unroll
        for (int i = 0; i < 4; ++i)
            #pragma unroll
            for (int j = 0; j < 4; ++j)
                acc[i][j] = __builtin_amdgcn_mfma_f32_16x16x32_bf16(
                    af[i], bf[j], acc[i][j], 0, 0, 0);
    }

    #pragma unroll
    for (int j = 0; j < 4; ++j) {
        const int c  = wn + j*16 + m15;
        const float bj = bo[c];
        #pragma unroll
        for (int i = 0; i < 4; ++i) {
            #pragma unroll
            for (int r = 0; r < 4; ++r) {
                const int row = rb + wm + i*16 + g*4 + r;
                float v = acc[i][j][r] + bj;
                out[row*DM + c] = v > 0.f ? v : 0.f;
            }
        }
    }
}

// ---------------------------------------------------------------------------
extern "C" void kernel_launch(void* const* d_in, const int* in_sizes, int n_in,
                              void* d_out, int out_size, void* d_ws, size_t ws_size,
                              hipStream_t stream)
{
    const float* X   = (const float*)d_in[0];
    const float* STE = (const float*)d_in[1];
    const float* Wq  = (const float*)d_in[2];
    const float* bq  = (const float*)d_in[3];
    const float* Wk  = (const float*)d_in[4];
    const float* bk  = (const float*)d_in[5];
    const float* Wv  = (const float*)d_in[6];
    const float* bv  = (const float*)d_in[7];
    const float* Wo  = (const float*)d_in[8];
    const float* bo  = (const float*)d_in[9];
    float* out = (float*)d_out;

    unsigned short* qb  = (unsigned short*)d_ws;
    unsigned short* kb  = qb  + (size_t)MR*DM;
    unsigned short* vb  = kb  + (size_t)MR*DM;
    unsigned short* ot  = vb  + (size_t)MR*DM;
    unsigned short* Wt  = ot  + (size_t)MR*DM;
    unsigned short* Wot = Wt  + (size_t)3*K3*DM;

    hipLaunchKernelGGL(wprep_kernel, dim3((3*K3*DM + DM*DM)/TB), dim3(TB), 0, stream,
                       Wq, Wk, Wv, Wo, Wt, Wot);
    hipLaunchKernelGGL(qkv_mfma, dim3(MR/128, 3), dim3(TB), 0, stream,
                       X, STE, Wt, bq, bk, bv, qb, kb, vb);
    hipLaunchKernelGGL(attn_kernel, dim3(KH*B_*T_), dim3(TB), 0, stream,
                       qb, kb, vb, ot);
    hipLaunchKernelGGL(out_mfma, dim3(MR/128), dim3(TB), 0, stream,
                       ot, Wot, bo, out);
}

// Round 6
// 190.742 us; speedup vs baseline: 1.1157x; 1.1157x over previous
//
#include <hip/hip_runtime.h>
#include <math.h>

// Problem constants (fixed by setup_inputs)
constexpr int B_  = 8;
constexpr int T_  = 12;
constexpr int N_  = 512;
constexpr int DM  = 128;      // d_model
constexpr int KH  = 8;        // heads
constexpr int DH  = 16;       // head dim
constexpr int MR  = B_*T_*N_; // 49152 rows
constexpr int K3  = 3*DM;     // 384
constexpr int TB  = 256;

typedef __attribute__((ext_vector_type(8))) short  bf16x8;
typedef __attribute__((ext_vector_type(4))) float  f32x4;
typedef __attribute__((ext_vector_type(4))) int    i32x4;

// log2(e) and the constant softmax shift (in log2 domain)
#define LOG2E 1.44269504088896340736f
#define SHIFT2 28.8539008177792681f     /* 20 * log2(e) */

// raw v_exp_f32 (2^x). exp2f() lowers to OCML's precise multi-instruction
// __ocml_exp2_f32 (round-5 regression: VALUBusy 60->68); the builtin is 1 op.
static __device__ inline float fast_exp2(float x) {
#if __has_builtin(__builtin_amdgcn_exp2f)
    return __builtin_amdgcn_exp2f(x);
#else
    return __expf(0.69314718055994531f * x);   // v_mul + v_exp
#endif
}

// fp32 -> bf16 RNE (inputs here are finite, non-NaN)
static __device__ inline unsigned short f2bf(float x) {
    unsigned u = __float_as_uint(x);
    return (unsigned short)((u + 0x7fffu + ((u >> 16) & 1u)) >> 16);
}
// pack two fp32 -> bf16x2 dword, round half up (a -> low16, b -> high16)
static __device__ inline unsigned pk2(float a, float b) {
    unsigned ua = __float_as_uint(a) + 0x8000u;
    unsigned ub = __float_as_uint(b) + 0x8000u;
    return __builtin_amdgcn_perm(ub, ua, 0x07060302u);
}
// pack two fp32 -> bf16x2 dword, TRUNCATE (1 v_perm). Used for P: the
// truncation bias cancels since l sums the same truncated values.
static __device__ inline unsigned pk2t(float a, float b) {
    return __builtin_amdgcn_perm(__float_as_uint(b), __float_as_uint(a),
                                 0x07060302u);
}
static __device__ inline float fast_rcp(float x) {
#if __has_builtin(__builtin_amdgcn_rcpf)
    return __builtin_amdgcn_rcpf(x);
#else
    return 1.0f / x;
#endif
}

// ---------------------------------------------------------------------------
// Kernel 0: weight prep. Wt[p][n][k] = bf16(W_p[k][n]); Wot[n][k] = bf16(Wo[k][n]).
// ---------------------------------------------------------------------------
__global__ __launch_bounds__(256) void wprep_kernel(
    const float* __restrict__ Wq, const float* __restrict__ Wk,
    const float* __restrict__ Wv, const float* __restrict__ Wo,
    unsigned short* __restrict__ Wt, unsigned short* __restrict__ Wot)
{
    const int idx = blockIdx.x*256 + threadIdx.x;
    if (idx < 3*K3*DM) {
        const int p   = idx / (K3*DM);
        const int rem = idx - p*(K3*DM);     // k*128 + n
        const int k   = rem >> 7;
        const int n   = rem & 127;
        const float* W = (p == 0) ? Wq : ((p == 1) ? Wk : Wv);
        Wt[p*(K3*DM) + n*K3 + k] = f2bf(W[rem]);
    } else {
        const int i2 = idx - 3*K3*DM;        // k*128 + n
        const int k  = i2 >> 7;
        const int n  = i2 & 127;
        Wot[n*DM + k] = f2bf(Wo[i2]);
    }
}

// ---------------------------------------------------------------------------
// Kernel 1: q/k/v = relu([X|STE] @ W{q,k,v} + b) via bf16 MFMA.
// Tile 128x128x(K=64 chunks); 4 waves 2x2. H fp32->bf16 during staging.
// Output head-major bf16 [KH][MR][DH]; q pre-scaled by 0.25*log2(e) so the
// attention scores come out of the S-MFMA already in log2 domain.
// ---------------------------------------------------------------------------
__global__ __launch_bounds__(256, 2) void qkv_mfma(
    const float* __restrict__ X, const float* __restrict__ STE,
    const unsigned short* __restrict__ Wt,
    const float* __restrict__ bq, const float* __restrict__ bk,
    const float* __restrict__ bv,
    unsigned short* __restrict__ qb, unsigned short* __restrict__ kb2,
    unsigned short* __restrict__ vb2)
{
    __shared__ __align__(16) unsigned short Ash[128*72];  // [m][k] 18 KB
    __shared__ __align__(16) unsigned short Bsh[128*72];  // [n][k] 18 KB
    const int tid = threadIdx.x;
    const int rb  = blockIdx.x * 128;
    const int p   = blockIdx.y;            // 0:q 1:k 2:v (uniform)
    const unsigned short* __restrict__ wtp = Wt + p*(K3*DM);
    const float* __restrict__ bias = (p == 0) ? bq : ((p == 1) ? bk : bv);
    unsigned short* __restrict__ outb = (p == 0) ? qb : ((p == 1) ? kb2 : vb2);
    const float scale = (p == 0) ? (0.25f * LOG2E) : 1.0f;

    const int lane = tid & 63, wv = tid >> 6;
    const int wm = (wv >> 1)*64, wn = (wv & 1)*64;
    const int m15 = lane & 15, g = lane >> 4;

    f32x4 acc[4][4] = {};

    for (int kt = 0; kt < K3; kt += 64) {
        const float* __restrict__ src = (kt < DM) ? (X + kt) : (STE + (kt - DM));
        const int ldr = (kt < DM) ? DM : 2*DM;
        #pragma unroll
        for (int i = 0; i < 8; ++i) {
            const int idx = tid + i*TB;
            const int m   = idx >> 4;
            const int c4  = idx & 15;
            const float4 f = *(const float4*)(src + (rb + m)*ldr + c4*4);
            uint2 d2;
            d2.x = pk2(f.x, f.y);
            d2.y = pk2(f.z, f.w);
            *(uint2*)(Ash + m*72 + c4*4) = d2;
        }
        #pragma unroll
        for (int i = 0; i < 4; ++i) {
            const int idx = tid + i*TB;
            const int n   = idx >> 3;
            const int kg  = idx & 7;
            *(uint4*)(Bsh + n*72 + kg*8) =
                *(const uint4*)(wtp + n*K3 + kt + kg*8);
        }
        __syncthreads();
        #pragma unroll
        for (int ks = 0; ks < 64; ks += 32) {
            bf16x8 af[4], bf[4];
            #pragma unroll
            for (int i = 0; i < 4; ++i)
                af[i] = *(const bf16x8*)(Ash + (wm + i*16 + m15)*72 + ks + g*8);
            #pragma unroll
            for (int j = 0; j < 4; ++j)
                bf[j] = *(const bf16x8*)(Bsh + (wn + j*16 + m15)*72 + ks + g*8);
            #pragma unroll
            for (int i = 0; i < 4; ++i)
                #pragma unroll
                for (int j = 0; j < 4; ++j)
                    acc[i][j] = __builtin_amdgcn_mfma_f32_16x16x32_bf16(
                        af[i], bf[j], acc[i][j], 0, 0, 0);
        }
        __syncthreads();
    }

    #pragma unroll
    for (int j = 0; j < 4; ++j) {
        const int c  = wn + j*16 + m15;
        const float bj = bias[c];
        const int h = c >> 4, d = c & 15;
        #pragma unroll
        for (int i = 0; i < 4; ++i) {
            #pragma unroll
            for (int r = 0; r < 4; ++r) {
                const int row = rb + wm + i*16 + g*4 + r;
                float v = acc[i][j][r] + bj;
                v = (v > 0.f ? v : 0.f) * scale;
                outb[(h*MR + row)*DH + d] = f2bf(v);
            }
        }
    }
}

// ---------------------------------------------------------------------------
// Kernel 2: MFMA attention.
//  - S-MFMA accumulator seeded with -SHIFT2: p = 2^s, no per-elem sub.
//  - exp via raw v_exp_f32 builtin (round-6 fix; exp2f was OCML-slow).
//  - l computed by a ones-MFMA: lacc rows == O-acc rows on the same lane,
//    so normalization needs no shuffles at all.
//  - P packed to bf16 by truncation (1 v_perm/pair); bias cancels in l.
// ---------------------------------------------------------------------------
__global__ __launch_bounds__(256, 3) void attn_kernel(
    const unsigned short* __restrict__ qb, const unsigned short* __restrict__ kb,
    const unsigned short* __restrict__ vb, unsigned short* __restrict__ ob)
{
    __shared__ __align__(16) unsigned short Klds[N_*DH];    // 16 KB
    __shared__ __align__(16) unsigned short Vtlds[DH*536];  // [d][key]

    const int tid = threadIdx.x;
    const int h   = blockIdx.x & (KH-1);
    const int bt  = blockIdx.x >> 3;
    const int base = (h*MR + bt*N_) * DH;

    {
        const uint4* kg = (const uint4*)(kb + base);
        uint4* kl = (uint4*)Klds;
        #pragma unroll
        for (int i = 0; i < 4; ++i) kl[tid + i*TB] = kg[tid + i*TB];
    }
    {
        const unsigned* vg = (const unsigned*)(vb + base);
        unsigned a[8], b[8];
        #pragma unroll
        for (int j = 0; j < 8; ++j) {
            a[j] = vg[(2*tid)*8 + j];
            b[j] = vg[(2*tid+1)*8 + j];
        }
        unsigned* vt = (unsigned*)Vtlds;
        #pragma unroll
        for (int d = 0; d < 16; ++d) {
            const int sh = (d & 1) * 16;
            const unsigned lo = (a[d >> 1] >> sh) & 0xffffu;
            const unsigned hi = (b[d >> 1] >> sh) & 0xffffu;
            vt[d*268 + tid] = lo | (hi << 16);
        }
    }
    __syncthreads();

    const int wv   = tid >> 6;
    const int lane = tid & 63;
    const int m    = lane & 15;
    const int g    = lane >> 4;

    bf16x8 qf[8];
    const unsigned short* qp = qb + base;
    #pragma unroll
    for (int j = 0; j < 8; ++j) {
        bf16x8 t = {0,0,0,0,0,0,0,0};
        if (g < 2) t = *(const bf16x8*)(qp + ((wv*8 + j)*16 + m)*DH + g*8);
        qf[j] = t;
    }

    const bf16x8 ones = {0x3F80,0x3F80,0x3F80,0x3F80,0x3F80,0x3F80,0x3F80,0x3F80};
    const f32x4 zshift = {-SHIFT2, -SHIFT2, -SHIFT2, -SHIFT2};

    f32x4 acc[8]  = {};
    f32x4 lacc[8] = {};

    for (int c = 0; c < 16; ++c) {
        const int kr0 = c*32 + ((m & 12) << 1) + (m & 3);
        bf16x8 kf0 = {0,0,0,0,0,0,0,0};
        bf16x8 kf1 = {0,0,0,0,0,0,0,0};
        if (g < 2) {
            kf0 = *(const bf16x8*)(Klds + kr0*DH + g*8);
            kf1 = *(const bf16x8*)(Klds + (kr0 + 4)*DH + g*8);
        }
        const bf16x8 vf = *(const bf16x8*)(Vtlds + m*536 + c*32 + g*8);

        #pragma unroll
        for (int j = 0; j < 8; ++j) {
            f32x4 s0 = __builtin_amdgcn_mfma_f32_16x16x32_bf16(kf0, qf[j], zshift, 0, 0, 0);
            f32x4 s1 = __builtin_amdgcn_mfma_f32_16x16x32_bf16(kf1, qf[j], zshift, 0, 0, 0);
            // lane holds S2[q=m][key = c*32 + 8g + r (+4 for s1)] - SHIFT2
            const float p0 = fast_exp2(s0[0]);
            const float p1 = fast_exp2(s0[1]);
            const float p2 = fast_exp2(s0[2]);
            const float p3 = fast_exp2(s0[3]);
            const float p4 = fast_exp2(s1[0]);
            const float p5 = fast_exp2(s1[1]);
            const float p6 = fast_exp2(s1[2]);
            const float p7 = fast_exp2(s1[3]);
            i32x4 pd = { (int)pk2t(p0, p1), (int)pk2t(p2, p3),
                         (int)pk2t(p4, p5), (int)pk2t(p6, p7) };
            const bf16x8 pf = __builtin_bit_cast(bf16x8, pd);
            acc[j]  = __builtin_amdgcn_mfma_f32_16x16x32_bf16(pf, vf,   acc[j],  0, 0, 0);
            lacc[j] = __builtin_amdgcn_mfma_f32_16x16x32_bf16(pf, ones, lacc[j], 0, 0, 0);
        }
    }

    // epilogue: rows of lacc coincide with rows of acc on this lane.
    #pragma unroll
    for (int j = 0; j < 8; ++j) {
        #pragma unroll
        for (int r = 0; r < 4; ++r) {
            const float iv = fast_rcp(lacc[j][r]);
            const int qrow = bt*N_ + (wv*8 + j)*16 + 4*g + r;
            ob[qrow*DM + h*DH + m] = f2bf(acc[j][r] * iv);
        }
    }
}

// ---------------------------------------------------------------------------
// Kernel 3: out = relu(o @ Wo + bo) via bf16 MFMA. K=128 one staging phase.
// ---------------------------------------------------------------------------
__global__ __launch_bounds__(256, 2) void out_mfma(
    const unsigned short* __restrict__ ot, const unsigned short* __restrict__ Wot,
    const float* __restrict__ bo, float* __restrict__ out)
{
    __shared__ __align__(16) unsigned short Ash[128*136];  // 34 KB
    __shared__ __align__(16) unsigned short Bsh[128*136];  // 34 KB
    const int tid = threadIdx.x;
    const int rb  = blockIdx.x * 128;
    const int lane = tid & 63, wv = tid >> 6;
    const int wm = (wv >> 1)*64, wn = (wv & 1)*64;
    const int m15 = lane & 15, g = lane >> 4;

    #pragma unroll
    for (int i = 0; i < 8; ++i) {
        const int idx = tid + i*TB;          // 0..2047
        const int r  = idx >> 4;             // 0..127
        const int kg = idx & 15;             // 0..15
        *(uint4*)(Ash + r*136 + kg*8) = *(const uint4*)(ot + (rb + r)*DM + kg*8);
        *(uint4*)(Bsh + r*136 + kg*8) = *(const uint4*)(Wot + r*DM + kg*8);
    }
    __syncthreads();

    f32x4 acc[4][4] = {};
    #pragma unroll
    for (int ks = 0; ks < 128; ks += 32) {
        bf16x8 af[4], bf[4];
        #pragma unroll
        for (int i = 0; i < 4; ++i)
            af[i] = *(const bf16x8*)(Ash + (wm + i*16 + m15)*136 + ks + g*8);
        #pragma unroll
        for (int j = 0; j < 4; ++j)
            bf[j] = *(const bf16x8*)(Bsh + (wn + j*16 + m15)*136 + ks + g*8);
        #pragma unroll
        for (int i = 0; i < 4; ++i)
            #pragma unroll
            for (int j = 0; j < 4; ++j)
                acc[i][j] = __builtin_amdgcn_mfma_f32_16x16x32_bf16(
                    af[i], bf[j], acc[i][j], 0, 0, 0);
    }

    #pragma unroll
    for (int j = 0; j < 4; ++j) {
        const int c  = wn + j*16 + m15;
        const float bj = bo[c];
        #pragma unroll
        for (int i = 0; i < 4; ++i) {
            #pragma unroll
            for (int r = 0; r < 4; ++r) {
                const int row = rb + wm + i*16 + g*4 + r;
                float v = acc[i][j][r] + bj;
                out[row*DM + c] = v > 0.f ? v : 0.f;
            }
        }
    }
}

// ---------------------------------------------------------------------------
extern "C" void kernel_launch(void* const* d_in, const int* in_sizes, int n_in,
                              void* d_out, int out_size, void* d_ws, size_t ws_size,
                              hipStream_t stream)
{
    const float* X   = (const float*)d_in[0];
    const float* STE = (const float*)d_in[1];
    const float* Wq  = (const float*)d_in[2];
    const float* bq  = (const float*)d_in[3];
    const float* Wk  = (const float*)d_in[4];
    const float* bk  = (const float*)d_in[5];
    const float* Wv  = (const float*)d_in[6];
    const float* bv  = (const float*)d_in[7];
    const float* Wo  = (const float*)d_in[8];
    const float* bo  = (const float*)d_in[9];
    float* out = (float*)d_out;

    unsigned short* qb  = (unsigned short*)d_ws;
    unsigned short* kb  = qb  + (size_t)MR*DM;
    unsigned short* vb  = kb  + (size_t)MR*DM;
    unsigned short* ot  = vb  + (size_t)MR*DM;
    unsigned short* Wt  = ot  + (size_t)MR*DM;
    unsigned short* Wot = Wt  + (size_t)3*K3*DM;

    hipLaunchKernelGGL(wprep_kernel, dim3((3*K3*DM + DM*DM)/TB), dim3(TB), 0, stream,
                       Wq, Wk, Wv, Wo, Wt, Wot);
    hipLaunchKernelGGL(qkv_mfma, dim3(MR/128, 3), dim3(TB), 0, stream,
                       X, STE, Wt, bq, bk, bv, qb, kb, vb);
    hipLaunchKernelGGL(attn_kernel, dim3(KH*B_*T_), dim3(TB), 0, stream,
                       qb, kb, vb, ot);
    hipLaunchKernelGGL(out_mfma, dim3(MR/128), dim3(TB), 0, stream,
                       ot, Wot, bo, out);
}